// Round 17
// baseline (535.352 us; speedup 1.0000x reference)
//
#include <hip/hip_runtime.h>
#include <hip/hip_bf16.h>

// Graph-transformer MHA layer. N=50000, E=1600000, IN_DIM=64, H=8, D=8.
// Outputs: h_out [N*64] then e_out [E*64], fp32, concatenated in d_out.
//
// R17 (from R16):
//  - edge kernel launched with 1280 blocks (5120 waves, all co-resident at
//    5 blocks/CU) instead of 6250 (1 tile/wave). Each wave now grid-strides
//    ~5 tiles: the 64-load We->Afr prologue amortizes 5x (was ~19% of wave
//    lifetime), and the grid-stride loop + dbuf LDS + __restrict__ outputs
//    let the compiler overlap iteration k+1's loads with iteration k's tail.
//  - everything else = R16 (dbuf LDS, K/Q preload, fused proj+rank, scan,
//    reorder, 8-wide aggregate).

using short8 = __attribute__((ext_vector_type(8))) short;
using f32x16 = __attribute__((ext_vector_type(16))) float;

__device__ __forceinline__ short f2bf(float f) {
    __hip_bfloat16 b = __float2bfloat16(f);     // RNE; pairs fuse to v_cvt_pk_bf16_f32
    return __builtin_bit_cast(short, b);
}

// ---------------- fused node projection (y=0..2) + rank (y=3) ----------------
__global__ __launch_bounds__(256)
void proj_rank_kernel(const float* __restrict__ hsrc,
                      const float* __restrict__ Wq, const float* __restrict__ bq,
                      const float* __restrict__ Wk, const float* __restrict__ bk,
                      const float* __restrict__ Wv, const float* __restrict__ bv,
                      float* __restrict__ Q, float* __restrict__ K, float* __restrict__ V,
                      const int* __restrict__ dst, int* __restrict__ counts,
                      int* __restrict__ rank, int n, int E)
{
    if (blockIdx.y == 3) {
        int i = blockIdx.x * 256 + threadIdx.x;
        const int stride = gridDim.x * 256;
        for (; i < E; i += stride) {
            rank[i] = atomicAdd(&counts[dst[i]], 1);
        }
        return;
    }

    const float* W;
    const float* b;
    float* out;
    if (blockIdx.y == 0)      { W = Wq; b = bq; out = Q; }
    else if (blockIdx.y == 1) { W = Wk; b = bk; out = K; }
    else                      { W = Wv; b = bv; out = V; }

    const int t    = threadIdx.x;
    const int lane = t & 63;
    const int w    = t >> 6;

    float wcol[64];
#pragma unroll
    for (int k = 0; k < 64; ++k) wcol[k] = W[k * 64 + lane];
    const float bias = b[lane];

    __shared__ float4 sh[16][16];
    const float4* __restrict__ h4 = (const float4*)hsrc;

    const int ngroups = (n + 15) >> 4;
    for (int g = blockIdx.x; g < ngroups; g += gridDim.x) {
        const int base = g << 4;
        {
            const int rs = t >> 4, c4 = t & 15;
            float4 v = make_float4(0.f, 0.f, 0.f, 0.f);
            if (base + rs < n) v = h4[(size_t)(base + rs) * 16 + c4];
            __syncthreads();
            sh[rs][c4] = v;
            __syncthreads();
        }
        float acc0 = bias, acc1 = bias, acc2 = bias, acc3 = bias;
#pragma unroll
        for (int k4 = 0; k4 < 16; ++k4) {
            const float w0 = wcol[k4 * 4 + 0], w1 = wcol[k4 * 4 + 1];
            const float w2 = wcol[k4 * 4 + 2], w3 = wcol[k4 * 4 + 3];
            const float4 a = sh[w * 4 + 0][k4];
            const float4 bb = sh[w * 4 + 1][k4];
            const float4 c = sh[w * 4 + 2][k4];
            const float4 d = sh[w * 4 + 3][k4];
            acc0 = fmaf(a.w,  w3, fmaf(a.z,  w2, fmaf(a.y,  w1, fmaf(a.x,  w0, acc0))));
            acc1 = fmaf(bb.w, w3, fmaf(bb.z, w2, fmaf(bb.y, w1, fmaf(bb.x, w0, acc1))));
            acc2 = fmaf(c.w,  w3, fmaf(c.z,  w2, fmaf(c.y,  w1, fmaf(c.x,  w0, acc2))));
            acc3 = fmaf(d.w,  w3, fmaf(d.z,  w2, fmaf(d.y,  w1, fmaf(d.x,  w0, acc3))));
        }
        const int n0 = base + w * 4;
        if (n0 + 0 < n) out[(size_t)(n0 + 0) * 64 + lane] = acc0;
        if (n0 + 1 < n) out[(size_t)(n0 + 1) * 64 + lane] = acc1;
        if (n0 + 2 < n) out[(size_t)(n0 + 2) * 64 + lane] = acc2;
        if (n0 + 3 < n) out[(size_t)(n0 + 3) * 64 + lane] = acc3;
    }
}

// ---------------- multi-block exclusive scan (3 kernels) ----------------
__global__ __launch_bounds__(1024)
void scan1_kernel(const int* __restrict__ counts, int* __restrict__ offsets,
                  int* __restrict__ bsum, int n)
{
    const int t = threadIdx.x;
    const int lane = t & 63;
    const int w = t >> 6;
    __shared__ int wsum[16];
    const int i = blockIdx.x * 1024 + t;
    const int v = (i < n) ? counts[i] : 0;
    int x = v;
#pragma unroll
    for (int d = 1; d < 64; d <<= 1) {
        int y = __shfl_up(x, d);
        if (lane >= d) x += y;
    }
    if (lane == 63) wsum[w] = x;
    __syncthreads();
    if (w == 0 && lane < 16) {
        int s = wsum[lane];
#pragma unroll
        for (int d = 1; d < 16; d <<= 1) {
            int y = __shfl_up(s, d);
            if (lane >= d) s += y;
        }
        wsum[lane] = s;
    }
    __syncthreads();
    const int excl = ((w == 0) ? 0 : wsum[w - 1]) + (x - v);
    if (i < n) offsets[i] = excl;
    if (t == 1023) bsum[blockIdx.x] = excl + v;
}

__global__ __launch_bounds__(64)
void scan2_kernel(int* __restrict__ bsum, int nb)
{
    const int lane = threadIdx.x;
    const int v = (lane < nb) ? bsum[lane] : 0;
    int x = v;
#pragma unroll
    for (int d = 1; d < 64; d <<= 1) {
        int y = __shfl_up(x, d);
        if (lane >= d) x += y;
    }
    if (lane < nb) bsum[lane] = x - v;   // exclusive
}

__global__ __launch_bounds__(1024)
void scan3_kernel(int* __restrict__ offsets, const int* __restrict__ bsum,
                  int n, int E)
{
    const int i = blockIdx.x * 1024 + threadIdx.x;
    if (i < n) offsets[i] += bsum[blockIdx.x];
    if (blockIdx.x == 0 && threadIdx.x == 0) offsets[n] = E;
}

// ---------------- edge kernel v17: MFMA, dbuf LDS, multi-tile waves ----------------
__global__ __launch_bounds__(256)
void edge_kernel(const float* __restrict__ e,
                 const float* __restrict__ We, const float* __restrict__ be,
                 const int* __restrict__ src, const int* __restrict__ dst,
                 const float* __restrict__ Q, const float* __restrict__ K,
                 float* __restrict__ e_out, float* __restrict__ sg, int E)
{
    __shared__ float4 tile4[4][2][32 * 8];          // 2x4KB per wave, XOR-swizzled
    const int t    = threadIdx.x;
    const int lane = t & 63;
    const int wu   = __builtin_amdgcn_readfirstlane(t >> 6);
    const int lid  = lane & 31;
    const int hi   = lane >> 5;
    const float inv = 0.35355339059327373f;         // 1/sqrt(8)

    // A fragments (We^T), loaded once per wave, amortized over ~5 tiles.
    // A[jh][ks] elem (4g+i) holds We[k = 16ks + 8g + 4hi + i][j = 32jh + lid].
    short8 Afr[2][4];
#pragma unroll
    for (int jh = 0; jh < 2; ++jh)
#pragma unroll
        for (int ks = 0; ks < 4; ++ks)
#pragma unroll
            for (int g = 0; g < 2; ++g)
#pragma unroll
                for (int i = 0; i < 4; ++i)
                    Afr[jh][ks][4 * g + i] =
                        f2bf(We[(16 * ks + 8 * g + 4 * hi + i) * 64 + 32 * jh + lid]);

    const int ntiles = (E + 63) >> 6;
    for (int tb = blockIdx.x * 4 + wu; tb < ntiles; tb += gridDim.x * 4) {
        const int base = tb << 6;

#pragma unroll
        for (int eh = 0; eh < 2; ++eh) {
            const int erow_i = base + eh * 32 + lid;
            const int erc = erow_i < E ? erow_i : (E - 1);
            const int se = src[erc];
            const int de = dst[erc];

            // e row loads issued first
            const float* er = e + (size_t)erc * 64 + 4 * hi;
            float4 p0 = *(const float4*)(er + 0),  p1 = *(const float4*)(er + 8);
            float4 p2 = *(const float4*)(er + 16), p3 = *(const float4*)(er + 24);
            float4 p4 = *(const float4*)(er + 32), p5 = *(const float4*)(er + 40);
            float4 p6 = *(const float4*)(er + 48), p7 = *(const float4*)(er + 56);

            // K/Q rows for BOTH jh preloaded (16 independent gathers in flight)
            const float* kb = K + (size_t)se * 64 + 4 * hi;
            const float* qb = Q + (size_t)de * 64 + 4 * hi;
            float4 kv[2][4], qv[2][4];
#pragma unroll
            for (int jh = 0; jh < 2; ++jh)
#pragma unroll
                for (int hd = 0; hd < 4; ++hd) {
                    kv[jh][hd] = *(const float4*)(kb + 32 * jh + 8 * hd);
                    qv[jh][hd] = *(const float4*)(qb + 32 * jh + 8 * hd);
                }

            // cvt B fragments: elem (4g+i) = e[row][k = 16ks + 8g + 4hi + i]
            short8 Bfr[4];
#pragma unroll
            for (int ks = 0; ks < 4; ++ks) {
                const float4 pa = (ks == 0) ? p0 : (ks == 1) ? p2 : (ks == 2) ? p4 : p6;
                const float4 pb = (ks == 0) ? p1 : (ks == 1) ? p3 : (ks == 2) ? p5 : p7;
                Bfr[ks][0] = f2bf(pa.x); Bfr[ks][1] = f2bf(pa.y);
                Bfr[ks][2] = f2bf(pa.z); Bfr[ks][3] = f2bf(pa.w);
                Bfr[ks][4] = f2bf(pb.x); Bfr[ks][5] = f2bf(pb.y);
                Bfr[ks][6] = f2bf(pb.z); Bfr[ks][7] = f2bf(pb.w);
            }

            float gate[8];
#pragma unroll
            for (int jh = 0; jh < 2; ++jh) {
                // phase buffer: alternates each (eh,jh) phase -> WAR distance 2
                float4* const buf = tile4[wu][jh];

                f32x16 D = {};
#pragma unroll
                for (int ks = 0; ks < 4; ++ks)
                    D = __builtin_amdgcn_mfma_f32_32x32x16_bf16(
                            Afr[jh][ks], Bfr[ks], D, 0, 0, 0);

                // epilogue: preloaded kv/qv; stage + head sums
#pragma unroll
                for (int hd = 0; hd < 4; ++hd) {
                    const float4 bev = *(const float4*)(be + 32 * jh + 8 * hd + 4 * hi);
                    const float4 k4 = kv[jh][hd];
                    const float4 q4 = qv[jh][hd];
                    // reg r = 4*hd + i  ->  j_local(within jh) = 8*hd + 4*hi + i
                    const float s0 = k4.x * q4.x * inv * (D[4 * hd + 0] + bev.x);
                    const float s1 = k4.y * q4.y * inv * (D[4 * hd + 1] + bev.y);
                    const float s2 = k4.z * q4.z * inv * (D[4 * hd + 2] + bev.z);
                    const float s3 = k4.w * q4.w * inv * (D[4 * hd + 3] + bev.w);
                    const int c4 = (2 * hd + hi) ^ (lid & 7);       // XOR swizzle
                    buf[lid * 8 + c4] = make_float4(s0, s1, s2, s3);
                    float pp = (s0 + s1) + (s2 + s3);
                    const float full = pp + __shfl_xor(pp, 32);     // head = 4jh+hd
                    gate[jh * 4 + hd] = expf(fminf(fmaxf(full, -5.f), 5.f));
                }

                // readout: 4 x 64-lane dwordx4 stores of 128B half-rows
                const int r8 = lane >> 3, m = lane & 7;
#pragma unroll
                for (int it = 0; it < 4; ++it) {
                    const int row = it * 8 + r8;                    // edge row 0..31
                    const int edge2 = base + eh * 32 + row;
                    const float4 v = buf[row * 8 + (m ^ (row & 7))];
                    if (edge2 < E)
                        *((float4*)e_out + (size_t)edge2 * 16 + jh * 8 + m) = v;
                }
            }

            // coalesced gate write: 32 edges x 32B contiguous (1KB per phase)
            if (erow_i < E) {
                const float4 g = (hi == 0)
                    ? make_float4(gate[0], gate[1], gate[2], gate[3])
                    : make_float4(gate[4], gate[5], gate[6], gate[7]);
                *(float4*)(sg + (size_t)erow_i * 8 + hi * 4) = g;
            }
        }
    }
}

// ---------------- reorder kernel: coalesced read -> sorted scatter ----------------
__global__ __launch_bounds__(256)
void reorder_kernel(const float* __restrict__ sg, const int* __restrict__ src,
                    const int* __restrict__ dst, const int* __restrict__ rank,
                    const int* __restrict__ offs,
                    float* __restrict__ s_sorted, int* __restrict__ src_sorted,
                    int E)
{
    int i = blockIdx.x * 256 + threadIdx.x;
    const int stride = gridDim.x * 256;
    for (; i < E; i += stride) {
        const int rk = offs[dst[i]] + rank[i];
        const float4 g0 = *(const float4*)(sg + (size_t)i * 8);
        const float4 g1 = *(const float4*)(sg + (size_t)i * 8 + 4);
        *(float4*)(s_sorted + (size_t)rk * 8)     = g0;
        *(float4*)(s_sorted + (size_t)rk * 8 + 4) = g1;
        src_sorted[rk] = src[i];
    }
}

// ---------------- aggregation: one wave per node, 8-wide batching ----------------
__global__ __launch_bounds__(256)
void aggregate_kernel(const int* __restrict__ offsets,
                      const int* __restrict__ src_sorted,
                      const float* __restrict__ s_sorted,
                      const float* __restrict__ V,
                      float* __restrict__ hout, int n)
{
    const int w = (blockIdx.x * 256 + threadIdx.x) >> 6;
    const int lane = threadIdx.x & 63;
    if (w >= n) return;
    const int o0 = offsets[w], o1 = offsets[w + 1];
    const int head = lane >> 3;
    float acc = 0.f, zacc = 0.f;
    int j = o0;
    for (; j + 8 <= o1; j += 8) {
        int   sv[8];
        float ss[8];
#pragma unroll
        for (int q = 0; q < 8; ++q) {
            sv[q] = src_sorted[j + q];
            ss[q] = s_sorted[(size_t)(j + q) * 8 + head];
        }
        float vv[8];
#pragma unroll
        for (int q = 0; q < 8; ++q)
            vv[q] = V[(size_t)sv[q] * 64 + lane];
#pragma unroll
        for (int q = 0; q < 8; ++q) {
            acc = fmaf(vv[q], ss[q], acc);
            zacc += ss[q];
        }
    }
    for (; j < o1; ++j) {
        const int sv = src_sorted[j];
        const float s = s_sorted[(size_t)j * 8 + head];
        acc = fmaf(V[(size_t)sv * 64 + lane], s, acc);
        zacc += s;
    }
    hout[(size_t)w * 64 + lane] = acc / (zacc + 1e-6f);
}

extern "C" void kernel_launch(void* const* d_in, const int* in_sizes, int n_in,
                              void* d_out, int out_size, void* d_ws, size_t ws_size,
                              hipStream_t stream)
{
    const float* h  = (const float*)d_in[0];
    const float* e  = (const float*)d_in[1];
    const float* Wq = (const float*)d_in[2];
    const float* bq = (const float*)d_in[3];
    const float* Wk = (const float*)d_in[4];
    const float* bk = (const float*)d_in[5];
    const float* Wv = (const float*)d_in[6];
    const float* bv = (const float*)d_in[7];
    const float* We = (const float*)d_in[8];
    const float* be = (const float*)d_in[9];
    const int* src  = (const int*)d_in[10];
    const int* dst  = (const int*)d_in[11];

    const int N = in_sizes[0] / 64;
    const int E = in_sizes[1] / 64;

    float* hout  = (float*)d_out;                    // [N*64]
    float* e_out = (float*)d_out + (size_t)N * 64;   // [E*64]

    // workspace layout
    char* ws = (char*)d_ws;
    float* Q = (float*)ws;                 ws += (size_t)N * 64 * sizeof(float);
    float* K = (float*)ws;                 ws += (size_t)N * 64 * sizeof(float);
    float* V = (float*)ws;                 ws += (size_t)N * 64 * sizeof(float);
    float* sg = (float*)ws;                ws += (size_t)E * 8 * sizeof(float);
    float* s_sorted = (float*)ws;          ws += (size_t)E * 8 * sizeof(float);
    int* src_sorted = (int*)ws;            ws += (size_t)E * sizeof(int);
    int* rank = (int*)ws;                  ws += (size_t)E * sizeof(int);
    int* counts  = (int*)ws;               ws += (size_t)N * sizeof(int);
    int* offsets = (int*)ws;               ws += (size_t)(N + 1) * sizeof(int);
    int* bsum    = (int*)ws;               ws += 64 * sizeof(int);

    hipMemsetAsync(counts, 0, (size_t)N * sizeof(int), stream);

    // 1) fused Q,K,V projections + rank (independent, overlapped)
    proj_rank_kernel<<<dim3(512, 4), dim3(256), 0, stream>>>(
        h, Wq, bq, Wk, bk, Wv, bv, Q, K, V, dst, counts, rank, N, E);

    // 2) exclusive scan -> offsets (multi-block, 3 kernels)
    const int nb = (N + 1023) / 1024;
    scan1_kernel<<<dim3(nb), dim3(1024), 0, stream>>>(counts, offsets, bsum, N);
    scan2_kernel<<<dim3(1), dim3(64), 0, stream>>>(bsum, nb);
    scan3_kernel<<<dim3(nb), dim3(1024), 0, stream>>>(offsets, bsum, N, E);

    // 3) edge pass: MFMA, dbuf LDS, ~5 tiles per wave (Afr amortized,
    //    grid-stride loop provides cross-tile overlap)
    edge_kernel<<<dim3(1280), dim3(256), 0, stream>>>(
        e, We, be, src, dst, Q, K, e_out, sg, E);

    // 4) reorder: coalesced reads -> sorted scatter (TLP-rich)
    reorder_kernel<<<dim3(2048), dim3(256), 0, stream>>>(
        sg, src, dst, rank, offsets, s_sorted, src_sorted, E);

    // 5) aggregate per node (one wave each, 8-wide)
    const int ablocks = (N * 64 + 255) / 256;
    aggregate_kernel<<<dim3(ablocks), dim3(256), 0, stream>>>(
        offsets, src_sorted, s_sorted, V, hout, N);
}

// Round 18
// 533.612 us; speedup vs baseline: 1.0033x; 1.0033x over previous
//
#include <hip/hip_runtime.h>
#include <hip/hip_bf16.h>

// Graph-transformer MHA layer. N=50000, E=1600000, IN_DIM=64, H=8, D=8.
// Outputs: h_out [N*64] then e_out [E*64], fp32, concatenated in d_out.
//
// R18 (from R17):
//  - aggregate: 64-thread blocks (one wave = one node-segment). 256-thread
//    blocks held 4 Poisson(32) segments and retired at the max (~25-30%
//    idle-wave waste). Waves now retire independently; launch_bounds(64,8)
//    packs 8/SIMD.
//  - edge: next-tile src/dst/rank prefetch (3 ints/lane - too small to spill,
//    shortens the index->gather chain head). Otherwise R17 (plateaued ~265us;
//    1.6x traffic floor - structure accepted).
//  - rest unchanged.

using short8 = __attribute__((ext_vector_type(8))) short;
using f32x16 = __attribute__((ext_vector_type(16))) float;

__device__ __forceinline__ short f2bf(float f) {
    __hip_bfloat16 b = __float2bfloat16(f);     // RNE; pairs fuse to v_cvt_pk_bf16_f32
    return __builtin_bit_cast(short, b);
}

// ---------------- fused node projection (y=0..2) + rank (y=3) ----------------
__global__ __launch_bounds__(256)
void proj_rank_kernel(const float* __restrict__ hsrc,
                      const float* __restrict__ Wq, const float* __restrict__ bq,
                      const float* __restrict__ Wk, const float* __restrict__ bk,
                      const float* __restrict__ Wv, const float* __restrict__ bv,
                      float* __restrict__ Q, float* __restrict__ K, float* __restrict__ V,
                      const int* __restrict__ dst, int* __restrict__ counts,
                      int* __restrict__ rank, int n, int E)
{
    if (blockIdx.y == 3) {
        int i = blockIdx.x * 256 + threadIdx.x;
        const int stride = gridDim.x * 256;
        for (; i < E; i += stride) {
            rank[i] = atomicAdd(&counts[dst[i]], 1);
        }
        return;
    }

    const float* W;
    const float* b;
    float* out;
    if (blockIdx.y == 0)      { W = Wq; b = bq; out = Q; }
    else if (blockIdx.y == 1) { W = Wk; b = bk; out = K; }
    else                      { W = Wv; b = bv; out = V; }

    const int t    = threadIdx.x;
    const int lane = t & 63;
    const int w    = t >> 6;

    float wcol[64];
#pragma unroll
    for (int k = 0; k < 64; ++k) wcol[k] = W[k * 64 + lane];
    const float bias = b[lane];

    __shared__ float4 sh[16][16];
    const float4* __restrict__ h4 = (const float4*)hsrc;

    const int ngroups = (n + 15) >> 4;
    for (int g = blockIdx.x; g < ngroups; g += gridDim.x) {
        const int base = g << 4;
        {
            const int rs = t >> 4, c4 = t & 15;
            float4 v = make_float4(0.f, 0.f, 0.f, 0.f);
            if (base + rs < n) v = h4[(size_t)(base + rs) * 16 + c4];
            __syncthreads();
            sh[rs][c4] = v;
            __syncthreads();
        }
        float acc0 = bias, acc1 = bias, acc2 = bias, acc3 = bias;
#pragma unroll
        for (int k4 = 0; k4 < 16; ++k4) {
            const float w0 = wcol[k4 * 4 + 0], w1 = wcol[k4 * 4 + 1];
            const float w2 = wcol[k4 * 4 + 2], w3 = wcol[k4 * 4 + 3];
            const float4 a = sh[w * 4 + 0][k4];
            const float4 bb = sh[w * 4 + 1][k4];
            const float4 c = sh[w * 4 + 2][k4];
            const float4 d = sh[w * 4 + 3][k4];
            acc0 = fmaf(a.w,  w3, fmaf(a.z,  w2, fmaf(a.y,  w1, fmaf(a.x,  w0, acc0))));
            acc1 = fmaf(bb.w, w3, fmaf(bb.z, w2, fmaf(bb.y, w1, fmaf(bb.x, w0, acc1))));
            acc2 = fmaf(c.w,  w3, fmaf(c.z,  w2, fmaf(c.y,  w1, fmaf(c.x,  w0, acc2))));
            acc3 = fmaf(d.w,  w3, fmaf(d.z,  w2, fmaf(d.y,  w1, fmaf(d.x,  w0, acc3))));
        }
        const int n0 = base + w * 4;
        if (n0 + 0 < n) out[(size_t)(n0 + 0) * 64 + lane] = acc0;
        if (n0 + 1 < n) out[(size_t)(n0 + 1) * 64 + lane] = acc1;
        if (n0 + 2 < n) out[(size_t)(n0 + 2) * 64 + lane] = acc2;
        if (n0 + 3 < n) out[(size_t)(n0 + 3) * 64 + lane] = acc3;
    }
}

// ---------------- multi-block exclusive scan (3 kernels) ----------------
__global__ __launch_bounds__(1024)
void scan1_kernel(const int* __restrict__ counts, int* __restrict__ offsets,
                  int* __restrict__ bsum, int n)
{
    const int t = threadIdx.x;
    const int lane = t & 63;
    const int w = t >> 6;
    __shared__ int wsum[16];
    const int i = blockIdx.x * 1024 + t;
    const int v = (i < n) ? counts[i] : 0;
    int x = v;
#pragma unroll
    for (int d = 1; d < 64; d <<= 1) {
        int y = __shfl_up(x, d);
        if (lane >= d) x += y;
    }
    if (lane == 63) wsum[w] = x;
    __syncthreads();
    if (w == 0 && lane < 16) {
        int s = wsum[lane];
#pragma unroll
        for (int d = 1; d < 16; d <<= 1) {
            int y = __shfl_up(s, d);
            if (lane >= d) s += y;
        }
        wsum[lane] = s;
    }
    __syncthreads();
    const int excl = ((w == 0) ? 0 : wsum[w - 1]) + (x - v);
    if (i < n) offsets[i] = excl;
    if (t == 1023) bsum[blockIdx.x] = excl + v;
}

__global__ __launch_bounds__(64)
void scan2_kernel(int* __restrict__ bsum, int nb)
{
    const int lane = threadIdx.x;
    const int v = (lane < nb) ? bsum[lane] : 0;
    int x = v;
#pragma unroll
    for (int d = 1; d < 64; d <<= 1) {
        int y = __shfl_up(x, d);
        if (lane >= d) x += y;
    }
    if (lane < nb) bsum[lane] = x - v;   // exclusive
}

__global__ __launch_bounds__(1024)
void scan3_kernel(int* __restrict__ offsets, const int* __restrict__ bsum,
                  int n, int E)
{
    const int i = blockIdx.x * 1024 + threadIdx.x;
    if (i < n) offsets[i] += bsum[blockIdx.x];
    if (blockIdx.x == 0 && threadIdx.x == 0) offsets[n] = E;
}

// ---------------- edge kernel v18: MFMA, dbuf LDS, index prefetch ----------------
__global__ __launch_bounds__(256)
void edge_kernel(const float* __restrict__ e,
                 const float* __restrict__ We, const float* __restrict__ be,
                 const int* __restrict__ src, const int* __restrict__ dst,
                 const float* __restrict__ Q, const float* __restrict__ K,
                 float* __restrict__ e_out, float* __restrict__ sg, int E)
{
    __shared__ float4 tile4[4][2][32 * 8];          // 2x4KB per wave, XOR-swizzled
    const int t    = threadIdx.x;
    const int lane = t & 63;
    const int wu   = __builtin_amdgcn_readfirstlane(t >> 6);
    const int lid  = lane & 31;
    const int hi   = lane >> 5;
    const float inv = 0.35355339059327373f;         // 1/sqrt(8)

    // A fragments (We^T), loaded once per wave.
    // A[jh][ks] elem (4g+i) holds We[k = 16ks + 8g + 4hi + i][j = 32jh + lid].
    short8 Afr[2][4];
#pragma unroll
    for (int jh = 0; jh < 2; ++jh)
#pragma unroll
        for (int ks = 0; ks < 4; ++ks)
#pragma unroll
            for (int g = 0; g < 2; ++g)
#pragma unroll
                for (int i = 0; i < 4; ++i)
                    Afr[jh][ks][4 * g + i] =
                        f2bf(We[(16 * ks + 8 * g + 4 * hi + i) * 64 + 32 * jh + lid]);

    const int ntiles = (E + 63) >> 6;
    const int tstride = gridDim.x * 4;

    int tb = blockIdx.x * 4 + wu;
    if (tb >= ntiles) return;

    // current tile's indices (per eh half)
    int se_c[2], de_c[2];
#pragma unroll
    for (int eh = 0; eh < 2; ++eh) {
        const int erow_i = tb * 64 + eh * 32 + lid;
        const int erc = erow_i < E ? erow_i : (E - 1);
        se_c[eh] = src[erc];
        de_c[eh] = dst[erc];
    }

    for (; tb < ntiles; ) {
        const int base = tb << 6;
        const int tnext = tb + tstride;

        // prefetch next tile's indices early (3 ints/lane - no spill risk)
        int se_n[2], de_n[2];
        if (tnext < ntiles) {
#pragma unroll
            for (int eh = 0; eh < 2; ++eh) {
                const int erow_i = tnext * 64 + eh * 32 + lid;
                const int erc = erow_i < E ? erow_i : (E - 1);
                se_n[eh] = src[erc];
                de_n[eh] = dst[erc];
            }
        }

#pragma unroll
        for (int eh = 0; eh < 2; ++eh) {
            const int erow_i = base + eh * 32 + lid;
            const int erc = erow_i < E ? erow_i : (E - 1);
            const int se = se_c[eh];
            const int de = de_c[eh];

            // e row loads issued first
            const float* er = e + (size_t)erc * 64 + 4 * hi;
            float4 p0 = *(const float4*)(er + 0),  p1 = *(const float4*)(er + 8);
            float4 p2 = *(const float4*)(er + 16), p3 = *(const float4*)(er + 24);
            float4 p4 = *(const float4*)(er + 32), p5 = *(const float4*)(er + 40);
            float4 p6 = *(const float4*)(er + 48), p7 = *(const float4*)(er + 56);

            // K/Q rows for BOTH jh preloaded (16 independent gathers in flight)
            const float* kb = K + (size_t)se * 64 + 4 * hi;
            const float* qb = Q + (size_t)de * 64 + 4 * hi;
            float4 kv[2][4], qv[2][4];
#pragma unroll
            for (int jh = 0; jh < 2; ++jh)
#pragma unroll
                for (int hd = 0; hd < 4; ++hd) {
                    kv[jh][hd] = *(const float4*)(kb + 32 * jh + 8 * hd);
                    qv[jh][hd] = *(const float4*)(qb + 32 * jh + 8 * hd);
                }

            // cvt B fragments: elem (4g+i) = e[row][k = 16ks + 8g + 4hi + i]
            short8 Bfr[4];
#pragma unroll
            for (int ks = 0; ks < 4; ++ks) {
                const float4 pa = (ks == 0) ? p0 : (ks == 1) ? p2 : (ks == 2) ? p4 : p6;
                const float4 pb = (ks == 0) ? p1 : (ks == 1) ? p3 : (ks == 2) ? p5 : p7;
                Bfr[ks][0] = f2bf(pa.x); Bfr[ks][1] = f2bf(pa.y);
                Bfr[ks][2] = f2bf(pa.z); Bfr[ks][3] = f2bf(pa.w);
                Bfr[ks][4] = f2bf(pb.x); Bfr[ks][5] = f2bf(pb.y);
                Bfr[ks][6] = f2bf(pb.z); Bfr[ks][7] = f2bf(pb.w);
            }

            float gate[8];
#pragma unroll
            for (int jh = 0; jh < 2; ++jh) {
                // phase buffer alternates each (eh,jh) phase -> WAR distance 2
                float4* const buf = tile4[wu][jh];

                f32x16 D = {};
#pragma unroll
                for (int ks = 0; ks < 4; ++ks)
                    D = __builtin_amdgcn_mfma_f32_32x32x16_bf16(
                            Afr[jh][ks], Bfr[ks], D, 0, 0, 0);

                // epilogue: preloaded kv/qv; stage + head sums
#pragma unroll
                for (int hd = 0; hd < 4; ++hd) {
                    const float4 bev = *(const float4*)(be + 32 * jh + 8 * hd + 4 * hi);
                    const float4 k4 = kv[jh][hd];
                    const float4 q4 = qv[jh][hd];
                    const float s0 = k4.x * q4.x * inv * (D[4 * hd + 0] + bev.x);
                    const float s1 = k4.y * q4.y * inv * (D[4 * hd + 1] + bev.y);
                    const float s2 = k4.z * q4.z * inv * (D[4 * hd + 2] + bev.z);
                    const float s3 = k4.w * q4.w * inv * (D[4 * hd + 3] + bev.w);
                    const int c4 = (2 * hd + hi) ^ (lid & 7);       // XOR swizzle
                    buf[lid * 8 + c4] = make_float4(s0, s1, s2, s3);
                    float pp = (s0 + s1) + (s2 + s3);
                    const float full = pp + __shfl_xor(pp, 32);     // head = 4jh+hd
                    gate[jh * 4 + hd] = expf(fminf(fmaxf(full, -5.f), 5.f));
                }

                // readout: 4 x 64-lane dwordx4 stores of 128B half-rows
                const int r8 = lane >> 3, m = lane & 7;
#pragma unroll
                for (int it = 0; it < 4; ++it) {
                    const int row = it * 8 + r8;                    // edge row 0..31
                    const int edge2 = base + eh * 32 + row;
                    const float4 v = buf[row * 8 + (m ^ (row & 7))];
                    if (edge2 < E)
                        *((float4*)e_out + (size_t)edge2 * 16 + jh * 8 + m) = v;
                }
            }

            // coalesced gate write: 32 edges x 32B contiguous
            if (erow_i < E) {
                const float4 g = (hi == 0)
                    ? make_float4(gate[0], gate[1], gate[2], gate[3])
                    : make_float4(gate[4], gate[5], gate[6], gate[7]);
                *(float4*)(sg + (size_t)erow_i * 8 + hi * 4) = g;
            }
        }

        tb = tnext;
        se_c[0] = se_n[0]; se_c[1] = se_n[1];
        de_c[0] = de_n[0]; de_c[1] = de_n[1];
    }
}

// ---------------- reorder kernel: coalesced read -> sorted scatter ----------------
__global__ __launch_bounds__(256)
void reorder_kernel(const float* __restrict__ sg, const int* __restrict__ src,
                    const int* __restrict__ dst, const int* __restrict__ rank,
                    const int* __restrict__ offs,
                    float* __restrict__ s_sorted, int* __restrict__ src_sorted,
                    int E)
{
    int i = blockIdx.x * 256 + threadIdx.x;
    const int stride = gridDim.x * 256;
    for (; i < E; i += stride) {
        const int rk = offs[dst[i]] + rank[i];
        const float4 g0 = *(const float4*)(sg + (size_t)i * 8);
        const float4 g1 = *(const float4*)(sg + (size_t)i * 8 + 4);
        *(float4*)(s_sorted + (size_t)rk * 8)     = g0;
        *(float4*)(s_sorted + (size_t)rk * 8 + 4) = g1;
        src_sorted[rk] = src[i];
    }
}

// ---------------- aggregation: one wave per BLOCK per node ----------------
__global__ __launch_bounds__(64, 8)
void aggregate_kernel(const int* __restrict__ offsets,
                      const int* __restrict__ src_sorted,
                      const float* __restrict__ s_sorted,
                      const float* __restrict__ V,
                      float* __restrict__ hout, int n)
{
    const int w = blockIdx.x;           // one wave = one block = one node
    const int lane = threadIdx.x;
    if (w >= n) return;
    const int o0 = offsets[w], o1 = offsets[w + 1];
    const int head = lane >> 3;
    float acc = 0.f, zacc = 0.f;
    int j = o0;
    for (; j + 8 <= o1; j += 8) {
        int   sv[8];
        float ss[8];
#pragma unroll
        for (int q = 0; q < 8; ++q) {
            sv[q] = src_sorted[j + q];
            ss[q] = s_sorted[(size_t)(j + q) * 8 + head];
        }
        float vv[8];
#pragma unroll
        for (int q = 0; q < 8; ++q)
            vv[q] = V[(size_t)sv[q] * 64 + lane];
#pragma unroll
        for (int q = 0; q < 8; ++q) {
            acc = fmaf(vv[q], ss[q], acc);
            zacc += ss[q];
        }
    }
    for (; j < o1; ++j) {
        const int sv = src_sorted[j];
        const float s = s_sorted[(size_t)j * 8 + head];
        acc = fmaf(V[(size_t)sv * 64 + lane], s, acc);
        zacc += s;
    }
    hout[(size_t)w * 64 + lane] = acc / (zacc + 1e-6f);
}

extern "C" void kernel_launch(void* const* d_in, const int* in_sizes, int n_in,
                              void* d_out, int out_size, void* d_ws, size_t ws_size,
                              hipStream_t stream)
{
    const float* h  = (const float*)d_in[0];
    const float* e  = (const float*)d_in[1];
    const float* Wq = (const float*)d_in[2];
    const float* bq = (const float*)d_in[3];
    const float* Wk = (const float*)d_in[4];
    const float* bk = (const float*)d_in[5];
    const float* Wv = (const float*)d_in[6];
    const float* bv = (const float*)d_in[7];
    const float* We = (const float*)d_in[8];
    const float* be = (const float*)d_in[9];
    const int* src  = (const int*)d_in[10];
    const int* dst  = (const int*)d_in[11];

    const int N = in_sizes[0] / 64;
    const int E = in_sizes[1] / 64;

    float* hout  = (float*)d_out;                    // [N*64]
    float* e_out = (float*)d_out + (size_t)N * 64;   // [E*64]

    // workspace layout
    char* ws = (char*)d_ws;
    float* Q = (float*)ws;                 ws += (size_t)N * 64 * sizeof(float);
    float* K = (float*)ws;                 ws += (size_t)N * 64 * sizeof(float);
    float* V = (float*)ws;                 ws += (size_t)N * 64 * sizeof(float);
    float* sg = (float*)ws;                ws += (size_t)E * 8 * sizeof(float);
    float* s_sorted = (float*)ws;          ws += (size_t)E * 8 * sizeof(float);
    int* src_sorted = (int*)ws;            ws += (size_t)E * sizeof(int);
    int* rank = (int*)ws;                  ws += (size_t)E * sizeof(int);
    int* counts  = (int*)ws;               ws += (size_t)N * sizeof(int);
    int* offsets = (int*)ws;               ws += (size_t)(N + 1) * sizeof(int);
    int* bsum    = (int*)ws;               ws += 64 * sizeof(int);

    hipMemsetAsync(counts, 0, (size_t)N * sizeof(int), stream);

    // 1) fused Q,K,V projections + rank (independent, overlapped)
    proj_rank_kernel<<<dim3(512, 4), dim3(256), 0, stream>>>(
        h, Wq, bq, Wk, bk, Wv, bv, Q, K, V, dst, counts, rank, N, E);

    // 2) exclusive scan -> offsets (multi-block, 3 kernels)
    const int nb = (N + 1023) / 1024;
    scan1_kernel<<<dim3(nb), dim3(1024), 0, stream>>>(counts, offsets, bsum, N);
    scan2_kernel<<<dim3(1), dim3(64), 0, stream>>>(bsum, nb);
    scan3_kernel<<<dim3(nb), dim3(1024), 0, stream>>>(offsets, bsum, N, E);

    // 3) edge pass: MFMA, dbuf LDS, index prefetch
    edge_kernel<<<dim3(1280), dim3(256), 0, stream>>>(
        e, We, be, src, dst, Q, K, e_out, sg, E);

    // 4) reorder: coalesced reads -> sorted scatter (TLP-rich)
    reorder_kernel<<<dim3(2048), dim3(256), 0, stream>>>(
        sg, src, dst, rank, offsets, s_sorted, src_sorted, E);

    // 5) aggregate: one 64-thread block per node (independent retirement)
    aggregate_kernel<<<dim3(N), dim3(64), 0, stream>>>(
        offsets, src_sorted, s_sorted, V, hout, N);
}

// Round 19
// 482.346 us; speedup vs baseline: 1.1099x; 1.1063x over previous
//
#include <hip/hip_runtime.h>
#include <hip/hip_bf16.h>

// Graph-transformer MHA layer. N=50000, E=1600000, IN_DIM=64, H=8, D=8.
// Outputs: h_out [N*64] then e_out [E*64], fp32, concatenated in d_out.
//
// R19 (from R18/R16):
//  - Q/K/V workspace tables stored as BF16 (internal only; outputs fp32).
//    Edge K/Q gathers halve (256->128B/edge), kv/qv preload VGPRs halve,
//    aggregate's V table shrinks 12.8->6.4MB (closer to 4MB per-XCD L2).
//    Math error budget: absmax 0.0625 -> ~0.1, threshold 0.284.
//  - edge loop reverted to R16 form (R18's index prefetch was neutral).
//  - rest = R18 (fused proj+rank, 3-kernel scan, reorder, 1-wave-per-node
//    aggregate).

using short8 = __attribute__((ext_vector_type(8))) short;
using f32x16 = __attribute__((ext_vector_type(16))) float;

__device__ __forceinline__ short f2bf(float f) {
    __hip_bfloat16 b = __float2bfloat16(f);     // RNE; pairs fuse to v_cvt_pk_bf16_f32
    return __builtin_bit_cast(short, b);
}
__device__ __forceinline__ float bf2f(unsigned short s) {
    unsigned u = ((unsigned)s) << 16;
    return __builtin_bit_cast(float, u);
}

// ---------------- fused node projection (y=0..2, bf16 out) + rank (y=3) ----------------
__global__ __launch_bounds__(256)
void proj_rank_kernel(const float* __restrict__ hsrc,
                      const float* __restrict__ Wq, const float* __restrict__ bq,
                      const float* __restrict__ Wk, const float* __restrict__ bk,
                      const float* __restrict__ Wv, const float* __restrict__ bv,
                      unsigned short* __restrict__ Q, unsigned short* __restrict__ K,
                      unsigned short* __restrict__ V,
                      const int* __restrict__ dst, int* __restrict__ counts,
                      int* __restrict__ rank, int n, int E)
{
    if (blockIdx.y == 3) {
        int i = blockIdx.x * 256 + threadIdx.x;
        const int stride = gridDim.x * 256;
        for (; i < E; i += stride) {
            rank[i] = atomicAdd(&counts[dst[i]], 1);
        }
        return;
    }

    const float* W;
    const float* b;
    unsigned short* out;
    if (blockIdx.y == 0)      { W = Wq; b = bq; out = Q; }
    else if (blockIdx.y == 1) { W = Wk; b = bk; out = K; }
    else                      { W = Wv; b = bv; out = V; }

    const int t    = threadIdx.x;
    const int lane = t & 63;
    const int w    = t >> 6;

    float wcol[64];
#pragma unroll
    for (int k = 0; k < 64; ++k) wcol[k] = W[k * 64 + lane];
    const float bias = b[lane];

    __shared__ float4 sh[16][16];
    const float4* __restrict__ h4 = (const float4*)hsrc;

    const int ngroups = (n + 15) >> 4;
    for (int g = blockIdx.x; g < ngroups; g += gridDim.x) {
        const int base = g << 4;
        {
            const int rs = t >> 4, c4 = t & 15;
            float4 v = make_float4(0.f, 0.f, 0.f, 0.f);
            if (base + rs < n) v = h4[(size_t)(base + rs) * 16 + c4];
            __syncthreads();
            sh[rs][c4] = v;
            __syncthreads();
        }
        float acc0 = bias, acc1 = bias, acc2 = bias, acc3 = bias;
#pragma unroll
        for (int k4 = 0; k4 < 16; ++k4) {
            const float w0 = wcol[k4 * 4 + 0], w1 = wcol[k4 * 4 + 1];
            const float w2 = wcol[k4 * 4 + 2], w3 = wcol[k4 * 4 + 3];
            const float4 a = sh[w * 4 + 0][k4];
            const float4 bb = sh[w * 4 + 1][k4];
            const float4 c = sh[w * 4 + 2][k4];
            const float4 d = sh[w * 4 + 3][k4];
            acc0 = fmaf(a.w,  w3, fmaf(a.z,  w2, fmaf(a.y,  w1, fmaf(a.x,  w0, acc0))));
            acc1 = fmaf(bb.w, w3, fmaf(bb.z, w2, fmaf(bb.y, w1, fmaf(bb.x, w0, acc1))));
            acc2 = fmaf(c.w,  w3, fmaf(c.z,  w2, fmaf(c.y,  w1, fmaf(c.x,  w0, acc2))));
            acc3 = fmaf(d.w,  w3, fmaf(d.z,  w2, fmaf(d.y,  w1, fmaf(d.x,  w0, acc3))));
        }
        const int n0 = base + w * 4;
        if (n0 + 0 < n) out[(size_t)(n0 + 0) * 64 + lane] = (unsigned short)f2bf(acc0);
        if (n0 + 1 < n) out[(size_t)(n0 + 1) * 64 + lane] = (unsigned short)f2bf(acc1);
        if (n0 + 2 < n) out[(size_t)(n0 + 2) * 64 + lane] = (unsigned short)f2bf(acc2);
        if (n0 + 3 < n) out[(size_t)(n0 + 3) * 64 + lane] = (unsigned short)f2bf(acc3);
    }
}

// ---------------- multi-block exclusive scan (3 kernels) ----------------
__global__ __launch_bounds__(1024)
void scan1_kernel(const int* __restrict__ counts, int* __restrict__ offsets,
                  int* __restrict__ bsum, int n)
{
    const int t = threadIdx.x;
    const int lane = t & 63;
    const int w = t >> 6;
    __shared__ int wsum[16];
    const int i = blockIdx.x * 1024 + t;
    const int v = (i < n) ? counts[i] : 0;
    int x = v;
#pragma unroll
    for (int d = 1; d < 64; d <<= 1) {
        int y = __shfl_up(x, d);
        if (lane >= d) x += y;
    }
    if (lane == 63) wsum[w] = x;
    __syncthreads();
    if (w == 0 && lane < 16) {
        int s = wsum[lane];
#pragma unroll
        for (int d = 1; d < 16; d <<= 1) {
            int y = __shfl_up(s, d);
            if (lane >= d) s += y;
        }
        wsum[lane] = s;
    }
    __syncthreads();
    const int excl = ((w == 0) ? 0 : wsum[w - 1]) + (x - v);
    if (i < n) offsets[i] = excl;
    if (t == 1023) bsum[blockIdx.x] = excl + v;
}

__global__ __launch_bounds__(64)
void scan2_kernel(int* __restrict__ bsum, int nb)
{
    const int lane = threadIdx.x;
    const int v = (lane < nb) ? bsum[lane] : 0;
    int x = v;
#pragma unroll
    for (int d = 1; d < 64; d <<= 1) {
        int y = __shfl_up(x, d);
        if (lane >= d) x += y;
    }
    if (lane < nb) bsum[lane] = x - v;   // exclusive
}

__global__ __launch_bounds__(1024)
void scan3_kernel(int* __restrict__ offsets, const int* __restrict__ bsum,
                  int n, int E)
{
    const int i = blockIdx.x * 1024 + threadIdx.x;
    if (i < n) offsets[i] += bsum[blockIdx.x];
    if (blockIdx.x == 0 && threadIdx.x == 0) offsets[n] = E;
}

// ---------------- edge kernel v19: MFMA, dbuf LDS, bf16 K/Q gathers ----------------
__global__ __launch_bounds__(256)
void edge_kernel(const float* __restrict__ e,
                 const float* __restrict__ We, const float* __restrict__ be,
                 const int* __restrict__ src, const int* __restrict__ dst,
                 const unsigned short* __restrict__ Q,
                 const unsigned short* __restrict__ K,
                 float* __restrict__ e_out, float* __restrict__ sg, int E)
{
    __shared__ float4 tile4[4][2][32 * 8];          // 2x4KB per wave, XOR-swizzled
    const int t    = threadIdx.x;
    const int lane = t & 63;
    const int wu   = __builtin_amdgcn_readfirstlane(t >> 6);
    const int lid  = lane & 31;
    const int hi   = lane >> 5;
    const float inv = 0.35355339059327373f;         // 1/sqrt(8)

    // A fragments (We^T), loaded once per wave.
    // A[jh][ks] elem (4g+i) holds We[k = 16ks + 8g + 4hi + i][j = 32jh + lid].
    short8 Afr[2][4];
#pragma unroll
    for (int jh = 0; jh < 2; ++jh)
#pragma unroll
        for (int ks = 0; ks < 4; ++ks)
#pragma unroll
            for (int g = 0; g < 2; ++g)
#pragma unroll
                for (int i = 0; i < 4; ++i)
                    Afr[jh][ks][4 * g + i] =
                        f2bf(We[(16 * ks + 8 * g + 4 * hi + i) * 64 + 32 * jh + lid]);

    const int ntiles = (E + 63) >> 6;
    for (int tb = blockIdx.x * 4 + wu; tb < ntiles; tb += gridDim.x * 4) {
        const int base = tb << 6;

#pragma unroll
        for (int eh = 0; eh < 2; ++eh) {
            const int erow_i = base + eh * 32 + lid;
            const int erc = erow_i < E ? erow_i : (E - 1);
            const int se = src[erc];
            const int de = dst[erc];

            // e row loads issued first
            const float* er = e + (size_t)erc * 64 + 4 * hi;
            float4 p0 = *(const float4*)(er + 0),  p1 = *(const float4*)(er + 8);
            float4 p2 = *(const float4*)(er + 16), p3 = *(const float4*)(er + 24);
            float4 p4 = *(const float4*)(er + 32), p5 = *(const float4*)(er + 40);
            float4 p6 = *(const float4*)(er + 48), p7 = *(const float4*)(er + 56);

            // K/Q bf16 rows for BOTH jh preloaded (16 x 8B gathers in flight)
            const unsigned short* kb = K + (size_t)se * 64 + 4 * hi;
            const unsigned short* qb = Q + (size_t)de * 64 + 4 * hi;
            ushort4 kvr[2][4], qvr[2][4];
#pragma unroll
            for (int jh = 0; jh < 2; ++jh)
#pragma unroll
                for (int hd = 0; hd < 4; ++hd) {
                    kvr[jh][hd] = *(const ushort4*)(kb + 32 * jh + 8 * hd);
                    qvr[jh][hd] = *(const ushort4*)(qb + 32 * jh + 8 * hd);
                }

            // cvt B fragments: elem (4g+i) = e[row][k = 16ks + 8g + 4hi + i]
            short8 Bfr[4];
#pragma unroll
            for (int ks = 0; ks < 4; ++ks) {
                const float4 pa = (ks == 0) ? p0 : (ks == 1) ? p2 : (ks == 2) ? p4 : p6;
                const float4 pb = (ks == 0) ? p1 : (ks == 1) ? p3 : (ks == 2) ? p5 : p7;
                Bfr[ks][0] = f2bf(pa.x); Bfr[ks][1] = f2bf(pa.y);
                Bfr[ks][2] = f2bf(pa.z); Bfr[ks][3] = f2bf(pa.w);
                Bfr[ks][4] = f2bf(pb.x); Bfr[ks][5] = f2bf(pb.y);
                Bfr[ks][6] = f2bf(pb.z); Bfr[ks][7] = f2bf(pb.w);
            }

            float gate[8];
#pragma unroll
            for (int jh = 0; jh < 2; ++jh) {
                // phase buffer alternates each (eh,jh) phase -> WAR distance 2
                float4* const buf = tile4[wu][jh];

                f32x16 D = {};
#pragma unroll
                for (int ks = 0; ks < 4; ++ks)
                    D = __builtin_amdgcn_mfma_f32_32x32x16_bf16(
                            Afr[jh][ks], Bfr[ks], D, 0, 0, 0);

                // epilogue: preloaded bf16 kv/qv; stage + head sums
#pragma unroll
                for (int hd = 0; hd < 4; ++hd) {
                    const float4 bev = *(const float4*)(be + 32 * jh + 8 * hd + 4 * hi);
                    const ushort4 kr = kvr[jh][hd];
                    const ushort4 qr = qvr[jh][hd];
                    const float s0 = bf2f(kr.x) * bf2f(qr.x) * inv * (D[4 * hd + 0] + bev.x);
                    const float s1 = bf2f(kr.y) * bf2f(qr.y) * inv * (D[4 * hd + 1] + bev.y);
                    const float s2 = bf2f(kr.z) * bf2f(qr.z) * inv * (D[4 * hd + 2] + bev.z);
                    const float s3 = bf2f(kr.w) * bf2f(qr.w) * inv * (D[4 * hd + 3] + bev.w);
                    const int c4 = (2 * hd + hi) ^ (lid & 7);       // XOR swizzle
                    buf[lid * 8 + c4] = make_float4(s0, s1, s2, s3);
                    float pp = (s0 + s1) + (s2 + s3);
                    const float full = pp + __shfl_xor(pp, 32);     // head = 4jh+hd
                    gate[jh * 4 + hd] = expf(fminf(fmaxf(full, -5.f), 5.f));
                }

                // readout: 4 x 64-lane dwordx4 stores of 128B half-rows
                const int r8 = lane >> 3, m = lane & 7;
#pragma unroll
                for (int it = 0; it < 4; ++it) {
                    const int row = it * 8 + r8;                    // edge row 0..31
                    const int edge2 = base + eh * 32 + row;
                    const float4 v = buf[row * 8 + (m ^ (row & 7))];
                    if (edge2 < E)
                        *((float4*)e_out + (size_t)edge2 * 16 + jh * 8 + m) = v;
                }
            }

            // coalesced gate write: 32 edges x 32B contiguous
            if (erow_i < E) {
                const float4 g = (hi == 0)
                    ? make_float4(gate[0], gate[1], gate[2], gate[3])
                    : make_float4(gate[4], gate[5], gate[6], gate[7]);
                *(float4*)(sg + (size_t)erow_i * 8 + hi * 4) = g;
            }
        }
    }
}

// ---------------- reorder kernel: coalesced read -> sorted scatter ----------------
__global__ __launch_bounds__(256)
void reorder_kernel(const float* __restrict__ sg, const int* __restrict__ src,
                    const int* __restrict__ dst, const int* __restrict__ rank,
                    const int* __restrict__ offs,
                    float* __restrict__ s_sorted, int* __restrict__ src_sorted,
                    int E)
{
    int i = blockIdx.x * 256 + threadIdx.x;
    const int stride = gridDim.x * 256;
    for (; i < E; i += stride) {
        const int rk = offs[dst[i]] + rank[i];
        const float4 g0 = *(const float4*)(sg + (size_t)i * 8);
        const float4 g1 = *(const float4*)(sg + (size_t)i * 8 + 4);
        *(float4*)(s_sorted + (size_t)rk * 8)     = g0;
        *(float4*)(s_sorted + (size_t)rk * 8 + 4) = g1;
        src_sorted[rk] = src[i];
    }
}

// ---------------- aggregation: one wave per node, bf16 V gathers ----------------
__global__ __launch_bounds__(64, 8)
void aggregate_kernel(const int* __restrict__ offsets,
                      const int* __restrict__ src_sorted,
                      const float* __restrict__ s_sorted,
                      const unsigned short* __restrict__ V,
                      float* __restrict__ hout, int n)
{
    const int w = blockIdx.x;           // one wave = one block = one node
    const int lane = threadIdx.x;
    if (w >= n) return;
    const int o0 = offsets[w], o1 = offsets[w + 1];
    const int head = lane >> 3;
    float acc = 0.f, zacc = 0.f;
    int j = o0;
    for (; j + 8 <= o1; j += 8) {
        int   sv[8];
        float ss[8];
#pragma unroll
        for (int q = 0; q < 8; ++q) {
            sv[q] = src_sorted[j + q];
            ss[q] = s_sorted[(size_t)(j + q) * 8 + head];
        }
        float vv[8];
#pragma unroll
        for (int q = 0; q < 8; ++q)
            vv[q] = bf2f(V[(size_t)sv[q] * 64 + lane]);
#pragma unroll
        for (int q = 0; q < 8; ++q) {
            acc = fmaf(vv[q], ss[q], acc);
            zacc += ss[q];
        }
    }
    for (; j < o1; ++j) {
        const int sv = src_sorted[j];
        const float s = s_sorted[(size_t)j * 8 + head];
        acc = fmaf(bf2f(V[(size_t)sv * 64 + lane]), s, acc);
        zacc += s;
    }
    hout[(size_t)w * 64 + lane] = acc / (zacc + 1e-6f);
}

extern "C" void kernel_launch(void* const* d_in, const int* in_sizes, int n_in,
                              void* d_out, int out_size, void* d_ws, size_t ws_size,
                              hipStream_t stream)
{
    const float* h  = (const float*)d_in[0];
    const float* e  = (const float*)d_in[1];
    const float* Wq = (const float*)d_in[2];
    const float* bq = (const float*)d_in[3];
    const float* Wk = (const float*)d_in[4];
    const float* bk = (const float*)d_in[5];
    const float* Wv = (const float*)d_in[6];
    const float* bv = (const float*)d_in[7];
    const float* We = (const float*)d_in[8];
    const float* be = (const float*)d_in[9];
    const int* src  = (const int*)d_in[10];
    const int* dst  = (const int*)d_in[11];

    const int N = in_sizes[0] / 64;
    const int E = in_sizes[1] / 64;

    float* hout  = (float*)d_out;                    // [N*64]
    float* e_out = (float*)d_out + (size_t)N * 64;   // [E*64]

    // workspace layout
    char* ws = (char*)d_ws;
    unsigned short* Q = (unsigned short*)ws; ws += (size_t)N * 64 * sizeof(unsigned short);
    unsigned short* K = (unsigned short*)ws; ws += (size_t)N * 64 * sizeof(unsigned short);
    unsigned short* V = (unsigned short*)ws; ws += (size_t)N * 64 * sizeof(unsigned short);
    float* sg = (float*)ws;                ws += (size_t)E * 8 * sizeof(float);
    float* s_sorted = (float*)ws;          ws += (size_t)E * 8 * sizeof(float);
    int* src_sorted = (int*)ws;            ws += (size_t)E * sizeof(int);
    int* rank = (int*)ws;                  ws += (size_t)E * sizeof(int);
    int* counts  = (int*)ws;               ws += (size_t)N * sizeof(int);
    int* offsets = (int*)ws;               ws += (size_t)(N + 1) * sizeof(int);
    int* bsum    = (int*)ws;               ws += 64 * sizeof(int);

    hipMemsetAsync(counts, 0, (size_t)N * sizeof(int), stream);

    // 1) fused Q,K,V projections (bf16 out) + rank (independent, overlapped)
    proj_rank_kernel<<<dim3(512, 4), dim3(256), 0, stream>>>(
        h, Wq, bq, Wk, bk, Wv, bv, Q, K, V, dst, counts, rank, N, E);

    // 2) exclusive scan -> offsets (multi-block, 3 kernels)
    const int nb = (N + 1023) / 1024;
    scan1_kernel<<<dim3(nb), dim3(1024), 0, stream>>>(counts, offsets, bsum, N);
    scan2_kernel<<<dim3(1), dim3(64), 0, stream>>>(bsum, nb);
    scan3_kernel<<<dim3(nb), dim3(1024), 0, stream>>>(offsets, bsum, N, E);

    // 3) edge pass: MFMA, dbuf LDS, bf16 K/Q gathers
    edge_kernel<<<dim3(1280), dim3(256), 0, stream>>>(
        e, We, be, src, dst, Q, K, e_out, sg, E);

    // 4) reorder: coalesced reads -> sorted scatter (TLP-rich)
    reorder_kernel<<<dim3(2048), dim3(256), 0, stream>>>(
        sg, src, dst, rank, offsets, s_sorted, src_sorted, E);

    // 5) aggregate: one 64-thread block per node, bf16 V gathers
    aggregate_kernel<<<dim3(N), dim3(64), 0, stream>>>(
        offsets, src_sorted, s_sorted, V, hout, N);
}